// Round 20
// baseline (1717.410 us; speedup 1.0000x reference)
//
#include <hip/hip_runtime.h>
#include <hip/hip_bf16.h>

#define B_ 16
#define S_ 1024
#define IN_ 64
#define D_ 512
#define H_ 8
#define HD_ 64
#define FF_ 2048
#define L_ 6
#define OUT_ 256
#define BS_ (B_*S_)

typedef __attribute__((ext_vector_type(8))) short s16x8;
typedef __attribute__((ext_vector_type(4))) short s16x4;
typedef __attribute__((ext_vector_type(4))) float f32x4;

#define AS1(p) ((const __attribute__((address_space(1))) void*)(p))
#define AS3(p) ((__attribute__((address_space(3))) void*)(p))

__device__ __forceinline__ ushort f2bf(float x) {
  __hip_bfloat16 h = __float2bfloat16(x);
  return *reinterpret_cast<ushort*>(&h);
}
__device__ __forceinline__ float bf2f(ushort u) {
  unsigned v = ((unsigned)u) << 16;
  union { unsigned u; float f; } c; c.u = v; return c.f;
}
__device__ __forceinline__ float gelu_exact(float x) {
  return 0.5f * x * (1.0f + erff(x * 0.70710678118654752f));
}

// ---------------------------------------------------------------------------
// 128^2 GEMM, BK=32, 2-deep LDS dbuf + counted vmcnt(4) + raw s_barrier
// (r14-proven schedule). C[M,N] = A[M,K]*Bt[N,K]^T + bias.
// Split-K via blockIdx.z: z-th segment reads cols [z*K, (z+1)*K) and writes
// C + z*sCz (bias applied only on z==0). Epilogue stages C in LDS.
// MODE 1: bf16; MODE 2: gelu bf16; MODE 3: V transpose+permute -> vt.
// ---------------------------------------------------------------------------
template<int BN, int WM, int WN, int MODE>
__global__ __launch_bounds__(256)
void gemm_bt(const ushort* __restrict__ A, int lda,
             const ushort* __restrict__ Bt, int ldb,
             const float* __restrict__ bias,
             ushort* __restrict__ C, int ldc,
             int K, long sCz)
{
  constexpr int BM = 128;
  constexpr int BK = 32;
  constexpr int FM = BM / (WM * 16);
  constexpr int FN = BN / (WN * 16);
  constexpr int CP = 136;                 // C-stage row pitch (pad 8)
  __shared__ union {
    ushort ab[2][2][BM * BK];             // [buf][0=A,1=B]
    ushort c[BM * CP];
  } u;

  const int tid = threadIdx.x;
  const int lane = tid & 63;
  const int wave = tid >> 6;
  const int wr = wave / WN;
  const int wc = wave % WN;
  const int lrow = lane & 15;
  const int lk = (lane >> 4) * 8;

  // split-K segment
  const int kz = blockIdx.z;
  A += (size_t)kz * K;
  Bt += (size_t)kz * K;
  C += (size_t)kz * sCz;
  const float* biasz = (kz == 0) ? bias : nullptr;

  // XCD-aware bijective swizzle on (x,y) (all x*y grids here are %8==0)
  const int gx = gridDim.x;
  const int nwg = gx * gridDim.y;
  const int flat = blockIdx.y * gx + blockIdx.x;
  const int T = (flat & 7) * (nwg >> 3) + (flat >> 3);
  const int m0 = (T / gx) * BM;
  const int n0 = (T % gx) * BN;

  auto stage = [&](int bi, int k0) {
#pragma unroll
    for (int rr = 0; rr < 2; ++rr) {              // A half
      int c = rr * 256 + tid;
      int row = c >> 2, cg = c & 3;
      __builtin_amdgcn_global_load_lds(
          AS1(A + (size_t)(m0 + row) * lda + k0 + cg * 8),
          AS3(u.ab[bi][0] + (size_t)(rr * 256 + wave * 64) * 8), 16, 0, 0);
    }
#pragma unroll
    for (int rr = 0; rr < 2; ++rr) {              // B half
      int c = rr * 256 + tid;
      int row = c >> 2, cg = c & 3;
      __builtin_amdgcn_global_load_lds(
          AS1(Bt + (size_t)(n0 + row) * ldb + k0 + cg * 8),
          AS3(u.ab[bi][1] + (size_t)(rr * 256 + wave * 64) * 8), 16, 0, 0);
    }
  };

  f32x4 acc[FM][FN];
#pragma unroll
  for (int m = 0; m < FM; ++m)
#pragma unroll
    for (int n = 0; n < FN; ++n)
      acc[m][n] = (f32x4){0.f, 0.f, 0.f, 0.f};

  const int nt = K / BK;
  stage(0, 0);
  for (int t = 0; t < nt; ++t) {
    const int cur = t & 1;
    if (t + 1 < nt) {
      stage(cur ^ 1, (t + 1) * BK);
      asm volatile("s_waitcnt vmcnt(4)" ::: "memory");
    } else {
      asm volatile("s_waitcnt vmcnt(0)" ::: "memory");
    }
    __builtin_amdgcn_s_barrier();
    __builtin_amdgcn_sched_barrier(0);
    const ushort* Ac = u.ab[cur][0];
    const ushort* Bc = u.ab[cur][1];
    s16x8 a[FM], b[FN];
#pragma unroll
    for (int m = 0; m < FM; ++m)
      a[m] = *(const s16x8*)&Ac[(wr * FM * 16 + m * 16 + lrow) * BK + lk];
#pragma unroll
    for (int n = 0; n < FN; ++n)
      b[n] = *(const s16x8*)&Bc[(wc * FN * 16 + n * 16 + lrow) * BK + lk];
#pragma unroll
    for (int m = 0; m < FM; ++m)
#pragma unroll
      for (int n = 0; n < FN; ++n)
        acc[m][n] = __builtin_amdgcn_mfma_f32_16x16x32_bf16(a[m], b[n], acc[m][n], 0, 0, 0);
    __builtin_amdgcn_sched_barrier(0);
    __builtin_amdgcn_s_barrier();
  }

  // ---- epilogue: stage C tile in LDS, then coalesced / transposed writes ----
  __syncthreads();
  const int rbL = wr * FM * 16 + (lane >> 4) * 4;
  const int cbL = wc * FN * 16 + lrow;
#pragma unroll
  for (int n = 0; n < FN; ++n) {
    int colL = cbL + n * 16;
    float bv = biasz ? biasz[n0 + colL] : 0.0f;
#pragma unroll
    for (int m = 0; m < FM; ++m) {
#pragma unroll
      for (int r = 0; r < 4; ++r) {
        float v = acc[m][n][r] + bv;
        if (MODE == 2) v = gelu_exact(v);
        u.c[(rbL + m * 16 + r) * CP + colL] = f2bf(v);
      }
    }
  }
  __syncthreads();
  if (MODE == 3) {
    int dl = tid >> 1, kh = tid & 1;
    int vcol = n0 + dl;
    int bb = m0 >> 10, k0r = m0 & 1023;
    ushort* vrow = C + ((size_t)(bb * 8 + (vcol >> 6)) * HD_ + (vcol & 63)) * S_
                   + k0r + kh * 64;
#pragma unroll
    for (int w2 = 0; w2 < 2; ++w2)
#pragma unroll
      for (int g2 = 0; g2 < 4; ++g2) {
        ushort outv[8];
#pragma unroll
        for (int jj = 0; jj < 8; ++jj) {
          int pk = kh * 64 + w2 * 32 + (jj < 4 ? 4 * g2 + jj : 16 + 4 * g2 + (jj - 4));
          outv[jj] = u.c[pk * CP + dl];
        }
        *(s16x8*)(vrow + w2 * 32 + g2 * 8) = *(s16x8*)outv;
      }
  } else {
#pragma unroll
    for (int p = 0; p < 8; ++p) {
      int row = p * 16 + (tid >> 4);
      int col = (tid & 15) * 8;
      s16x8 v = *(const s16x8*)&u.c[row * CP + col];
      *(s16x8*)&C[(size_t)(m0 + row) * ldc + n0 + col] = v;
    }
  }
}

// ---------------------------------------------------------------------------
// Fused flash attention (r15-exact, 64.7us): 8 waves, QB=128; K/V staged via
// global_load_lds to LINEAR LDS, single-buffered, both-sides chunk-XOR
// swizzle; V pre-permuted so PV A-frag is ONE ds_read_b128; in-reg softmax.
// ---------------------------------------------------------------------------
__global__ __launch_bounds__(512)
void flash_kernel(const ushort* __restrict__ qkv, const ushort* __restrict__ vt,
                  ushort* __restrict__ ctx)
{
  constexpr int KB = 128;
  const float KE = 0.125f * 1.44269504f;
  __shared__ ushort ks[KB * 64];      // linear, chunk-XOR swizzled
  __shared__ ushort vs[HD_ * KB];     // linear, chunk-XOR swizzled
  const int tid = threadIdx.x;
  const int lane = tid & 63;
  const int wave = tid >> 6;        // 0..7
  const int lrow = lane & 15;
  const int g = lane >> 4;
  const int lk = g * 8;
  const int r7 = lrow & 7;

  // XCD swizzle (grid = 8 x 128, 1024 wgs)
  const int flat = blockIdx.y * 8 + blockIdx.x;
  const int T = (flat & 7) * 128 + (flat >> 3);
  const int bh = T >> 3;
  const int b = bh >> 3, h = bh & 7;
  const int q0 = (T & 7) * 128;

  s16x8 qf[2];
  {
    const ushort* qrow = qkv + ((size_t)(b * S_ + q0 + wave * 16 + lrow)) * (3 * D_) + h * HD_;
    s16x8 r0 = *(const s16x8*)(qrow + lk);
    s16x8 r1 = *(const s16x8*)(qrow + 32 + lk);
#pragma unroll
    for (int j = 0; j < 8; ++j) {
      qf[0][j] = (short)f2bf(bf2f((ushort)r0[j]) * KE);
      qf[1][j] = (short)f2bf(bf2f((ushort)r1[j]) * KE);
    }
  }
  float lsum = 0.f;
  f32x4 o[4] = {};

  for (int kt = 0; kt < S_ / KB; ++kt) {
    __syncthreads();                               // prev tile fully consumed
#pragma unroll
    for (int r = 0; r < 2; ++r) {                  // K tile
      int c = r * 512 + tid;
      int row = c >> 3, cc = c & 7;
      int scc = cc ^ (row & 7);
      __builtin_amdgcn_global_load_lds(
          AS1(qkv + ((size_t)(b * S_ + kt * KB + row)) * (3 * D_) + D_ + h * HD_ + scc * 8),
          AS3(ks + (size_t)(r * 512 + wave * 64) * 8), 16, 0, 0);
    }
#pragma unroll
    for (int r = 0; r < 2; ++r) {                  // V^T tile (pre-permuted)
      int c = r * 512 + tid;
      int row = c >> 4, cc = c & 15;
      int scc = cc ^ (row & 7);
      __builtin_amdgcn_global_load_lds(
          AS1(vt + ((size_t)(bh * HD_ + row)) * S_ + kt * KB + scc * 8),
          AS3(vs + (size_t)(r * 512 + wave * 64) * 8), 16, 0, 0);
    }
    __syncthreads();                               // drains vmcnt(0) + barrier

#pragma unroll
    for (int tp = 0; tp < 4; ++tp) {          // k-window of 32
      f32x4 s0 = {}, s1 = {};
      {
        int rb0 = tp * 32 + lrow;
        int rb1 = rb0 + 16;
        s16x8 k00 = *(const s16x8*)&ks[rb0 * 64 + ((g     ^ r7) * 8)];
        s16x8 k01 = *(const s16x8*)&ks[rb0 * 64 + (((g+4) ^ r7) * 8)];
        s16x8 k10 = *(const s16x8*)&ks[rb1 * 64 + ((g     ^ r7) * 8)];
        s16x8 k11 = *(const s16x8*)&ks[rb1 * 64 + (((g+4) ^ r7) * 8)];
        s0 = __builtin_amdgcn_mfma_f32_16x16x32_bf16(k00, qf[0], s0, 0, 0, 0);
        s0 = __builtin_amdgcn_mfma_f32_16x16x32_bf16(k01, qf[1], s0, 0, 0, 0);
        s1 = __builtin_amdgcn_mfma_f32_16x16x32_bf16(k10, qf[0], s1, 0, 0, 0);
        s1 = __builtin_amdgcn_mfma_f32_16x16x32_bf16(k11, qf[1], s1, 0, 0, 0);
      }
      union { s16x8 v; unsigned u[4]; } pa;
      {
        float p0 = exp2f(s0[0]), p1 = exp2f(s0[1]);
        float p2 = exp2f(s0[2]), p3 = exp2f(s0[3]);
        float p4 = exp2f(s1[0]), p5 = exp2f(s1[1]);
        float p6 = exp2f(s1[2]), p7 = exp2f(s1[3]);
        lsum += ((p0 + p1) + (p2 + p3)) + ((p4 + p5) + (p6 + p7));
        unsigned u0 = __float_as_uint(p0) + 0x8000u, u1 = __float_as_uint(p1) + 0x8000u;
        unsigned u2 = __float_as_uint(p2) + 0x8000u, u3 = __float_as_uint(p3) + 0x8000u;
        unsigned u4 = __float_as_uint(p4) + 0x8000u, u5 = __float_as_uint(p5) + 0x8000u;
        unsigned u6 = __float_as_uint(p6) + 0x8000u, u7 = __float_as_uint(p7) + 0x8000u;
        pa.u[0] = (u0 >> 16) | (u1 & 0xffff0000u);
        pa.u[1] = (u2 >> 16) | (u3 & 0xffff0000u);
        pa.u[2] = (u4 >> 16) | (u5 & 0xffff0000u);
        pa.u[3] = (u6 >> 16) | (u7 & 0xffff0000u);
      }
#pragma unroll
      for (int n2 = 0; n2 < 4; ++n2) {
        int vrow = n2 * 16 + lrow;
        s16x8 vf = *(const s16x8*)&vs[vrow * KB + (((tp * 4 + g) ^ r7) * 8)];
        o[n2] = __builtin_amdgcn_mfma_f32_16x16x32_bf16(vf, pa.v, o[n2], 0, 0, 0);
      }
    }
  }
  lsum += __shfl_xor(lsum, 16);
  lsum += __shfl_xor(lsum, 32);
  float inv = 1.0f / lsum;

  ushort* crow = ctx + ((size_t)(b * S_ + q0 + wave * 16 + lrow)) * D_ + h * HD_;
#pragma unroll
  for (int n2 = 0; n2 < 4; ++n2) {
    s16x4 w;
#pragma unroll
    for (int r = 0; r < 4; ++r) w[r] = (short)f2bf(o[n2][r] * inv);
    *(s16x4*)(crow + n2 * 16 + g * 4) = w;
  }
}

// a(bf16) (+a2 bf16) (+res bf16) -> LN -> (*g+b) -> (+pos) -> bf16 h
__global__ __launch_bounds__(256)
void ln512_kernel(const ushort* __restrict__ a, const ushort* __restrict__ a2,
                  const ushort* __restrict__ res,
                  const float* __restrict__ g, const float* __restrict__ bt,
                  const float* __restrict__ pos,
                  ushort* __restrict__ hout)
{
  const int row = blockIdx.x;
  const int t = threadIdx.x;
  const size_t base = (size_t)row * D_;
  float x0 = bf2f(a[base + t]), x1 = bf2f(a[base + t + 256]);
  if (a2) { x0 += bf2f(a2[base + t]); x1 += bf2f(a2[base + t + 256]); }
  if (res) { x0 += bf2f(res[base + t]); x1 += bf2f(res[base + t + 256]); }
  float s = x0 + x1, q = x0 * x0 + x1 * x1;
#pragma unroll
  for (int m = 32; m > 0; m >>= 1) { s += __shfl_xor(s, m); q += __shfl_xor(q, m); }
  __shared__ float red[8];
  if ((t & 63) == 0) { red[(t >> 6) * 2] = s; red[(t >> 6) * 2 + 1] = q; }
  __syncthreads();
  s = red[0] + red[2] + red[4] + red[6];
  q = red[1] + red[3] + red[5] + red[7];
  float mean = s * (1.0f / D_);
  float var = q * (1.0f / D_) - mean * mean;
  float rs = rsqrtf(var + 1e-5f);
  float y0 = (x0 - mean) * rs * g[t] + bt[t];
  float y1 = (x1 - mean) * rs * g[t + 256] + bt[t + 256];
  if (pos) {
    int sp = row & (S_ - 1);
    y0 += pos[(size_t)sp * D_ + t];
    y1 += pos[(size_t)sp * D_ + t + 256];
  }
  hout[base + t] = f2bf(y0);
  hout[base + t + 256] = f2bf(y1);
}

// W[K][N] fp32 -> Wt[N][K] bf16, batched over layers via blockIdx.z
__global__ void wtrans_kernel(const float* __restrict__ W, ushort* __restrict__ Wt, int K, int N)
{
  __shared__ float tile[32][33];
  const float* Wl = W + (size_t)blockIdx.z * K * N;
  ushort* Wtl = Wt + (size_t)blockIdx.z * K * N;
  int n0 = blockIdx.x * 32, k0 = blockIdx.y * 32;
  int tx = threadIdx.x, ty = threadIdx.y;  // 32 x 8
#pragma unroll
  for (int r = 0; r < 4; ++r)
    tile[ty * 4 + r][tx] = Wl[(size_t)(k0 + ty * 4 + r) * N + n0 + tx];
  __syncthreads();
#pragma unroll
  for (int r = 0; r < 4; ++r)
    Wtl[(size_t)(n0 + ty * 4 + r) * K + k0 + tx] = f2bf(tile[tx][ty * 4 + r]);
}

__global__ void castx_kernel(const float* __restrict__ x, ushort* __restrict__ xb, int n)
{
  int i = blockIdx.x * blockDim.x + threadIdx.x;
  if (i < n) xb[i] = f2bf(x[i]);
}

__global__ __launch_bounds__(256)
void pool_partial_kernel(const ushort* __restrict__ h, float* __restrict__ pp)
{
  int b = blockIdx.x, ch = blockIdx.y;
  int t = threadIdx.x;
  float s0 = 0, s1 = 0;
  for (int r = 0; r < 128; ++r) {
    size_t base = ((size_t)b * S_ + ch * 128 + r) * D_;
    s0 += bf2f(h[base + t]);
    s1 += bf2f(h[base + t + 256]);
  }
  pp[(size_t)(b * 8 + ch) * D_ + t] = s0;
  pp[(size_t)(b * 8 + ch) * D_ + t + 256] = s1;
}

__global__ __launch_bounds__(256)
void head_kernel(const float* __restrict__ pp,
                 const float* __restrict__ w1, const float* __restrict__ b1,
                 const float* __restrict__ lg, const float* __restrict__ lb,
                 const float* __restrict__ w2, const float* __restrict__ b2,
                 float* __restrict__ out)
{
  __shared__ float pooled[D_];
  __shared__ float z[256];
  int b = blockIdx.x, t = threadIdx.x;
  for (int i = t; i < D_; i += 256) {
    float s = 0;
    for (int c = 0; c < 8; ++c) s += pp[(size_t)(b * 8 + c) * D_ + i];
    pooled[i] = s * (1.0f / S_);
  }
  __syncthreads();
  float acc = 0;
  for (int k = 0; k < D_; ++k) acc += pooled[k] * w1[(size_t)k * 256 + t];
  float zz = gelu_exact(acc + b1[t]);
  float s = zz, q = zz * zz;
#pragma unroll
  for (int m = 32; m > 0; m >>= 1) { s += __shfl_xor(s, m); q += __shfl_xor(q, m); }
  __shared__ float red[8];
  if ((t & 63) == 0) { red[(t >> 6) * 2] = s; red[(t >> 6) * 2 + 1] = q; }
  __syncthreads();
  s = red[0] + red[2] + red[4] + red[6];
  q = red[1] + red[3] + red[5] + red[7];
  float mean = s * (1.0f / 256), var = q * (1.0f / 256) - mean * mean;
  float rs = rsqrtf(var + 1e-5f);
  z[t] = (zz - mean) * rs * lg[t] + lb[t];
  __syncthreads();
  float o = 0;
  for (int k = 0; k < 256; ++k) o += z[k] * w2[(size_t)k * 256 + t];
  out[(size_t)b * 256 + t] = o + b2[t];
}

extern "C" void kernel_launch(void* const* d_in, const int* in_sizes, int n_in,
                              void* d_out, int out_size, void* d_ws, size_t ws_size,
                              hipStream_t stream)
{
  const float* x       = (const float*)d_in[0];
  const float* in_w    = (const float*)d_in[1];
  const float* in_b    = (const float*)d_in[2];
  const float* in_ln_g = (const float*)d_in[3];
  const float* in_ln_b = (const float*)d_in[4];
  const float* pos     = (const float*)d_in[5];
  const float* qkv_w   = (const float*)d_in[6];
  const float* qkv_b   = (const float*)d_in[7];
  const float* ao_w    = (const float*)d_in[8];
  const float* ao_b    = (const float*)d_in[9];
  const float* ff_w1   = (const float*)d_in[10];
  const float* ff_b1   = (const float*)d_in[11];
  const float* ff_w2   = (const float*)d_in[12];
  const float* ff_b2   = (const float*)d_in[13];
  const float* ln1_g   = (const float*)d_in[14];
  const float* ln1_b   = (const float*)d_in[15];
  const float* ln2_g   = (const float*)d_in[16];
  const float* ln2_b   = (const float*)d_in[17];
  const float* o_w1    = (const float*)d_in[18];
  const float* o_b1    = (const float*)d_in[19];
  const float* o_ln_g  = (const float*)d_in[20];
  const float* o_ln_b  = (const float*)d_in[21];
  const float* o_w2    = (const float*)d_in[22];
  const float* o_b2    = (const float*)d_in[23];

  char* wp = (char*)d_ws;
  auto alloc = [&](size_t bytes) {
    char* p = wp;
    wp += (bytes + 255) & ~(size_t)255;
    return p;
  };
  ushort* hb     = (ushort*)alloc((size_t)BS_ * D_ * 2);   // residual stream (bf16)
  ushort* tmpb   = (ushort*)alloc((size_t)BS_ * D_ * 2);   // bf16 GEMM outs (z=0)
  ushort* tmpb2  = (ushort*)alloc((size_t)BS_ * D_ * 2);   // split-K partial (z=1)
  ushort* big    = (ushort*)alloc((size_t)BS_ * FF_ * 2);  // qkv (Q,K) / ff1 bf16
  ushort* ctxb   = (ushort*)alloc((size_t)BS_ * D_ * 2);
  ushort* xb     = (ushort*)alloc((size_t)BS_ * IN_ * 2);
  ushort* vt     = (ushort*)alloc((size_t)B_ * H_ * HD_ * S_ * 2);
  float*  pp     = (float*) alloc((size_t)B_ * 8 * D_ * 4);
  ushort* in_wt  = (ushort*)alloc((size_t)D_ * IN_ * 2);
  ushort* qkv_wt = (ushort*)alloc((size_t)L_ * 3 * D_ * D_ * 2);
  ushort* ao_wt  = (ushort*)alloc((size_t)L_ * D_ * D_ * 2);
  ushort* ff1_wt = (ushort*)alloc((size_t)L_ * FF_ * D_ * 2);
  ushort* ff2_wt = (ushort*)alloc((size_t)L_ * D_ * FF_ * 2);
  (void)ws_size; (void)n_in; (void)in_sizes; (void)out_size;

  dim3 wb(32, 8);
  wtrans_kernel<<<dim3(D_ / 32, IN_ / 32, 1), wb, 0, stream>>>(in_w, in_wt, IN_, D_);
  wtrans_kernel<<<dim3(3 * D_ / 32, D_ / 32, L_), wb, 0, stream>>>(qkv_w, qkv_wt, D_, 3 * D_);
  wtrans_kernel<<<dim3(D_ / 32, D_ / 32, L_), wb, 0, stream>>>(ao_w, ao_wt, D_, D_);
  wtrans_kernel<<<dim3(FF_ / 32, D_ / 32, L_), wb, 0, stream>>>(ff_w1, ff1_wt, D_, FF_);
  wtrans_kernel<<<dim3(D_ / 32, FF_ / 32, L_), wb, 0, stream>>>(ff_w2, ff2_wt, FF_, D_);
  castx_kernel<<<BS_ * IN_ / 256, 256, 0, stream>>>(x, xb, BS_ * IN_);

  // input projection -> bf16 (K=64: nt=2)
  gemm_bt<128, 2, 2, 1><<<dim3(D_ / 128, BS_ / 128, 1), 256, 0, stream>>>(
      xb, IN_, in_wt, IN_, in_b, tmpb, D_, IN_, 0);
  ln512_kernel<<<BS_, 256, 0, stream>>>(tmpb, nullptr, nullptr,
                                        in_ln_g, in_ln_b, pos, hb);

  const long sC = (long)BS_ * D_;
  for (int l = 0; l < L_; ++l) {
    const ushort* qwt = qkv_wt + (size_t)l * 3 * D_ * D_;
    const float*  qb  = qkv_b + (size_t)l * 3 * D_;
    // Q,K projection -> big cols [0,1024) (bf16)
    gemm_bt<128, 2, 2, 1><<<dim3(2 * D_ / 128, BS_ / 128, 1), 256, 0, stream>>>(
        hb, D_, qwt, D_, qb, big, 3 * D_, D_, 0);
    // V projection -> vt directly (transposed + pre-permuted)
    gemm_bt<128, 2, 2, 3><<<dim3(D_ / 128, BS_ / 128, 1), 256, 0, stream>>>(
        hb, D_, qwt + (size_t)(2 * D_) * D_, D_, qb + 2 * D_, vt, S_, D_, 0);
    // fused flash attention (QB=128)
    flash_kernel<<<dim3(S_ / 128, B_ * H_), 512, 0, stream>>>(big, vt, ctxb);
    // attention output projection: split-K=2 (2x occupancy)
    gemm_bt<128, 2, 2, 1><<<dim3(D_ / 128, BS_ / 128, 2), 256, 0, stream>>>(
        ctxb, D_, ao_wt + (size_t)l * D_ * D_, D_, ao_b + (size_t)l * D_,
        tmpb, D_, D_ / 2, sC);
    ln512_kernel<<<BS_, 256, 0, stream>>>(tmpb, tmpb2, hb, ln1_g + (size_t)l * D_,
                                          ln1_b + (size_t)l * D_, nullptr, hb);
    // FF1 (gelu, bf16)
    gemm_bt<128, 2, 2, 2><<<dim3(FF_ / 128, BS_ / 128, 1), 256, 0, stream>>>(
        hb, D_, ff1_wt + (size_t)l * FF_ * D_, D_, ff_b1 + (size_t)l * FF_,
        big, FF_, D_, 0);
    // FF2: split-K=2 (2x occupancy on the K=2048 GEMM)
    gemm_bt<128, 2, 2, 1><<<dim3(D_ / 128, BS_ / 128, 2), 256, 0, stream>>>(
        big, FF_, ff2_wt + (size_t)l * D_ * FF_, FF_, ff_b2 + (size_t)l * D_,
        tmpb, D_, FF_ / 2, sC);
    ln512_kernel<<<BS_, 256, 0, stream>>>(tmpb, tmpb2, hb, ln2_g + (size_t)l * D_,
                                          ln2_b + (size_t)l * D_, nullptr, hb);
  }
  pool_partial_kernel<<<dim3(B_, 8), 256, 0, stream>>>(hb, pp);
  head_kernel<<<B_, 256, 0, stream>>>(pp, o_w1, o_b1, o_ln_g, o_ln_b, o_w2, o_b2,
                                      (float*)d_out);
}

// Round 21
// 1618.840 us; speedup vs baseline: 1.0609x; 1.0609x over previous
//
#include <hip/hip_runtime.h>
#include <hip/hip_bf16.h>

#define B_ 16
#define S_ 1024
#define IN_ 64
#define D_ 512
#define H_ 8
#define HD_ 64
#define FF_ 2048
#define L_ 6
#define OUT_ 256
#define BS_ (B_*S_)

typedef __attribute__((ext_vector_type(8))) short s16x8;
typedef __attribute__((ext_vector_type(4))) short s16x4;
typedef __attribute__((ext_vector_type(4))) float f32x4;

#define AS1(p) ((const __attribute__((address_space(1))) void*)(p))
#define AS3(p) ((__attribute__((address_space(3))) void*)(p))

__device__ __forceinline__ ushort f2bf(float x) {
  __hip_bfloat16 h = __float2bfloat16(x);
  return *reinterpret_cast<ushort*>(&h);
}
__device__ __forceinline__ float bf2f(ushort u) {
  unsigned v = ((unsigned)u) << 16;
  union { unsigned u; float f; } c; c.u = v; return c.f;
}
__device__ __forceinline__ float gelu_exact(float x) {
  return 0.5f * x * (1.0f + erff(x * 0.70710678118654752f));
}

// ---------------------------------------------------------------------------
// 128^2 GEMM, BK=32, 2-deep LDS double-buffer + counted vmcnt(4) + raw
// s_barrier (T3-minimum recipe). C[M,N] = A[M,K]*Bt[N,K]^T + bias.
// Epilogue stages C in LDS. MODE 1: bf16; MODE 2: gelu bf16; MODE 3: V->vt.
// ---------------------------------------------------------------------------
template<int BN, int WM, int WN, int MODE>
__global__ __launch_bounds__(256)
void gemm_bt(const ushort* __restrict__ A, int lda,
             const ushort* __restrict__ Bt, int ldb,
             const float* __restrict__ bias,
             ushort* __restrict__ C, int ldc,
             int K)
{
  constexpr int BM = 128;
  constexpr int BK = 32;
  constexpr int FM = BM / (WM * 16);
  constexpr int FN = BN / (WN * 16);
  constexpr int CP = 136;                 // C-stage row pitch (pad 8)
  __shared__ union {
    ushort ab[2][2][BM * BK];             // [buf][0=A,1=B]
    ushort c[BM * CP];
  } u;

  const int tid = threadIdx.x;
  const int lane = tid & 63;
  const int wave = tid >> 6;
  const int wr = wave / WN;
  const int wc = wave % WN;
  const int lrow = lane & 15;
  const int lk = (lane >> 4) * 8;

  // XCD-aware bijective swizzle (all grids here have nwg % 8 == 0)
  const int gx = gridDim.x;
  const int nwg = gx * gridDim.y;
  const int flat = blockIdx.y * gx + blockIdx.x;
  const int T = (flat & 7) * (nwg >> 3) + (flat >> 3);
  const int m0 = (T / gx) * BM;
  const int n0 = (T % gx) * BN;

  auto stage = [&](int bi, int k0) {
#pragma unroll
    for (int rr = 0; rr < 2; ++rr) {              // A half
      int c = rr * 256 + tid;
      int row = c >> 2, cg = c & 3;
      __builtin_amdgcn_global_load_lds(
          AS1(A + (size_t)(m0 + row) * lda + k0 + cg * 8),
          AS3(u.ab[bi][0] + (size_t)(rr * 256 + wave * 64) * 8), 16, 0, 0);
    }
#pragma unroll
    for (int rr = 0; rr < 2; ++rr) {              // B half
      int c = rr * 256 + tid;
      int row = c >> 2, cg = c & 3;
      __builtin_amdgcn_global_load_lds(
          AS1(Bt + (size_t)(n0 + row) * ldb + k0 + cg * 8),
          AS3(u.ab[bi][1] + (size_t)(rr * 256 + wave * 64) * 8), 16, 0, 0);
    }
  };

  f32x4 acc[FM][FN];
#pragma unroll
  for (int m = 0; m < FM; ++m)
#pragma unroll
    for (int n = 0; n < FN; ++n)
      acc[m][n] = (f32x4){0.f, 0.f, 0.f, 0.f};

  const int nt = K / BK;
  stage(0, 0);
  for (int t = 0; t < nt; ++t) {
    const int cur = t & 1;
    if (t + 1 < nt) {
      stage(cur ^ 1, (t + 1) * BK);
      asm volatile("s_waitcnt vmcnt(4)" ::: "memory");
    } else {
      asm volatile("s_waitcnt vmcnt(0)" ::: "memory");
    }
    __builtin_amdgcn_s_barrier();
    __builtin_amdgcn_sched_barrier(0);
    const ushort* Ac = u.ab[cur][0];
    const ushort* Bc = u.ab[cur][1];
    s16x8 a[FM], b[FN];
#pragma unroll
    for (int m = 0; m < FM; ++m)
      a[m] = *(const s16x8*)&Ac[(wr * FM * 16 + m * 16 + lrow) * BK + lk];
#pragma unroll
    for (int n = 0; n < FN; ++n)
      b[n] = *(const s16x8*)&Bc[(wc * FN * 16 + n * 16 + lrow) * BK + lk];
#pragma unroll
    for (int m = 0; m < FM; ++m)
#pragma unroll
      for (int n = 0; n < FN; ++n)
        acc[m][n] = __builtin_amdgcn_mfma_f32_16x16x32_bf16(a[m], b[n], acc[m][n], 0, 0, 0);
    __builtin_amdgcn_sched_barrier(0);
    __builtin_amdgcn_s_barrier();
  }

  // ---- epilogue: stage C tile in LDS, then coalesced / transposed writes ----
  __syncthreads();
  const int rbL = wr * FM * 16 + (lane >> 4) * 4;
  const int cbL = wc * FN * 16 + lrow;
#pragma unroll
  for (int n = 0; n < FN; ++n) {
    int colL = cbL + n * 16;
    float bv = bias ? bias[n0 + colL] : 0.0f;
#pragma unroll
    for (int m = 0; m < FM; ++m) {
#pragma unroll
      for (int r = 0; r < 4; ++r) {
        float v = acc[m][n][r] + bv;
        if (MODE == 2) v = gelu_exact(v);
        u.c[(rbL + m * 16 + r) * CP + colL] = f2bf(v);
      }
    }
  }
  __syncthreads();
  if (MODE == 3) {
    int dl = tid >> 1, kh = tid & 1;
    int vcol = n0 + dl;
    int bb = m0 >> 10, k0r = m0 & 1023;
    ushort* vrow = C + ((size_t)(bb * 8 + (vcol >> 6)) * HD_ + (vcol & 63)) * S_
                   + k0r + kh * 64;
#pragma unroll
    for (int w2 = 0; w2 < 2; ++w2)
#pragma unroll
      for (int g2 = 0; g2 < 4; ++g2) {
        ushort outv[8];
#pragma unroll
        for (int jj = 0; jj < 8; ++jj) {
          int pk = kh * 64 + w2 * 32 + (jj < 4 ? 4 * g2 + jj : 16 + 4 * g2 + (jj - 4));
          outv[jj] = u.c[pk * CP + dl];
        }
        *(s16x8*)(vrow + w2 * 32 + g2 * 8) = *(s16x8*)outv;
      }
  } else {
#pragma unroll
    for (int p = 0; p < 8; ++p) {
      int row = p * 16 + (tid >> 4);
      int col = (tid & 15) * 8;
      s16x8 v = *(const s16x8*)&u.c[row * CP + col];
      *(s16x8*)&C[(size_t)(m0 + row) * ldc + n0 + col] = v;
    }
  }
}

// ---------------------------------------------------------------------------
// Fused flash attention (r15-exact, best measured 64.7us): 8 waves, QB=128;
// K/V staged via global_load_lds to LINEAR LDS, single-buffered, both-sides
// chunk-XOR swizzle; V pre-permuted so PV A-frag is ONE ds_read_b128;
// pa packed via bias+truncate bit-ops. In-register softmax, no max.
// ---------------------------------------------------------------------------
__global__ __launch_bounds__(512)
void flash_kernel(const ushort* __restrict__ qkv, const ushort* __restrict__ vt,
                  ushort* __restrict__ ctx)
{
  constexpr int KB = 128;
  const float KE = 0.125f * 1.44269504f;
  __shared__ ushort ks[KB * 64];      // linear, chunk-XOR swizzled
  __shared__ ushort vs[HD_ * KB];     // linear, chunk-XOR swizzled
  const int tid = threadIdx.x;
  const int lane = tid & 63;
  const int wave = tid >> 6;        // 0..7
  const int lrow = lane & 15;
  const int g = lane >> 4;
  const int lk = g * 8;
  const int r7 = lrow & 7;

  // XCD swizzle (grid = 8 x 128, 1024 wgs)
  const int flat = blockIdx.y * 8 + blockIdx.x;
  const int T = (flat & 7) * 128 + (flat >> 3);
  const int bh = T >> 3;
  const int b = bh >> 3, h = bh & 7;
  const int q0 = (T & 7) * 128;

  s16x8 qf[2];
  {
    const ushort* qrow = qkv + ((size_t)(b * S_ + q0 + wave * 16 + lrow)) * (3 * D_) + h * HD_;
    s16x8 r0 = *(const s16x8*)(qrow + lk);
    s16x8 r1 = *(const s16x8*)(qrow + 32 + lk);
#pragma unroll
    for (int j = 0; j < 8; ++j) {
      qf[0][j] = (short)f2bf(bf2f((ushort)r0[j]) * KE);
      qf[1][j] = (short)f2bf(bf2f((ushort)r1[j]) * KE);
    }
  }
  float lsum = 0.f;
  f32x4 o[4] = {};

  for (int kt = 0; kt < S_ / KB; ++kt) {
    __syncthreads();                               // prev tile fully consumed
#pragma unroll
    for (int r = 0; r < 2; ++r) {                  // K tile
      int c = r * 512 + tid;
      int row = c >> 3, cc = c & 7;
      int scc = cc ^ (row & 7);
      __builtin_amdgcn_global_load_lds(
          AS1(qkv + ((size_t)(b * S_ + kt * KB + row)) * (3 * D_) + D_ + h * HD_ + scc * 8),
          AS3(ks + (size_t)(r * 512 + wave * 64) * 8), 16, 0, 0);
    }
#pragma unroll
    for (int r = 0; r < 2; ++r) {                  // V^T tile (pre-permuted)
      int c = r * 512 + tid;
      int row = c >> 4, cc = c & 15;
      int scc = cc ^ (row & 7);
      __builtin_amdgcn_global_load_lds(
          AS1(vt + ((size_t)(bh * HD_ + row)) * S_ + kt * KB + scc * 8),
          AS3(vs + (size_t)(r * 512 + wave * 64) * 8), 16, 0, 0);
    }
    __syncthreads();                               // drains vmcnt(0) + barrier

#pragma unroll
    for (int tp = 0; tp < 4; ++tp) {          // k-window of 32
      f32x4 s0 = {}, s1 = {};
      {
        int rb0 = tp * 32 + lrow;
        int rb1 = rb0 + 16;                   // (rb1 & 7) == r7 too
        s16x8 k00 = *(const s16x8*)&ks[rb0 * 64 + ((g     ^ r7) * 8)];
        s16x8 k01 = *(const s16x8*)&ks[rb0 * 64 + (((g+4) ^ r7) * 8)];
        s16x8 k10 = *(const s16x8*)&ks[rb1 * 64 + ((g     ^ r7) * 8)];
        s16x8 k11 = *(const s16x8*)&ks[rb1 * 64 + (((g+4) ^ r7) * 8)];
        s0 = __builtin_amdgcn_mfma_f32_16x16x32_bf16(k00, qf[0], s0, 0, 0, 0);
        s0 = __builtin_amdgcn_mfma_f32_16x16x32_bf16(k01, qf[1], s0, 0, 0, 0);
        s1 = __builtin_amdgcn_mfma_f32_16x16x32_bf16(k10, qf[0], s1, 0, 0, 0);
        s1 = __builtin_amdgcn_mfma_f32_16x16x32_bf16(k11, qf[1], s1, 0, 0, 0);
      }
      union { s16x8 v; unsigned u[4]; } pa;
      {
        float p0 = exp2f(s0[0]), p1 = exp2f(s0[1]);
        float p2 = exp2f(s0[2]), p3 = exp2f(s0[3]);
        float p4 = exp2f(s1[0]), p5 = exp2f(s1[1]);
        float p6 = exp2f(s1[2]), p7 = exp2f(s1[3]);
        lsum += ((p0 + p1) + (p2 + p3)) + ((p4 + p5) + (p6 + p7));
        unsigned u0 = __float_as_uint(p0) + 0x8000u, u1 = __float_as_uint(p1) + 0x8000u;
        unsigned u2 = __float_as_uint(p2) + 0x8000u, u3 = __float_as_uint(p3) + 0x8000u;
        unsigned u4 = __float_as_uint(p4) + 0x8000u, u5 = __float_as_uint(p5) + 0x8000u;
        unsigned u6 = __float_as_uint(p6) + 0x8000u, u7 = __float_as_uint(p7) + 0x8000u;
        pa.u[0] = (u0 >> 16) | (u1 & 0xffff0000u);
        pa.u[1] = (u2 >> 16) | (u3 & 0xffff0000u);
        pa.u[2] = (u4 >> 16) | (u5 & 0xffff0000u);
        pa.u[3] = (u6 >> 16) | (u7 & 0xffff0000u);
      }
#pragma unroll
      for (int n2 = 0; n2 < 4; ++n2) {
        int vrow = n2 * 16 + lrow;
        s16x8 vf = *(const s16x8*)&vs[vrow * KB + (((tp * 4 + g) ^ r7) * 8)];
        o[n2] = __builtin_amdgcn_mfma_f32_16x16x32_bf16(vf, pa.v, o[n2], 0, 0, 0);
      }
    }
  }
  lsum += __shfl_xor(lsum, 16);
  lsum += __shfl_xor(lsum, 32);
  float inv = 1.0f / lsum;

  ushort* crow = ctx + ((size_t)(b * S_ + q0 + wave * 16 + lrow)) * D_ + h * HD_;
#pragma unroll
  for (int n2 = 0; n2 < 4; ++n2) {
    s16x4 w;
#pragma unroll
    for (int r = 0; r < 4; ++r) w[r] = (short)f2bf(o[n2][r] * inv);
    *(s16x4*)(crow + n2 * 16 + g * 4) = w;
  }
}

// a(bf16) (+res bf16) -> LN -> (*g+b) -> (+pos) -> bf16 h (single buffer)
__global__ __launch_bounds__(256)
void ln512_kernel(const ushort* __restrict__ a, const ushort* __restrict__ res,
                  const float* __restrict__ g, const float* __restrict__ bt,
                  const float* __restrict__ pos,
                  ushort* __restrict__ hout)
{
  const int row = blockIdx.x;
  const int t = threadIdx.x;
  const size_t base = (size_t)row * D_;
  float x0 = bf2f(a[base + t]), x1 = bf2f(a[base + t + 256]);
  if (res) { x0 += bf2f(res[base + t]); x1 += bf2f(res[base + t + 256]); }
  float s = x0 + x1, q = x0 * x0 + x1 * x1;
#pragma unroll
  for (int m = 32; m > 0; m >>= 1) { s += __shfl_xor(s, m); q += __shfl_xor(q, m); }
  __shared__ float red[8];
  if ((t & 63) == 0) { red[(t >> 6) * 2] = s; red[(t >> 6) * 2 + 1] = q; }
  __syncthreads();
  s = red[0] + red[2] + red[4] + red[6];
  q = red[1] + red[3] + red[5] + red[7];
  float mean = s * (1.0f / D_);
  float var = q * (1.0f / D_) - mean * mean;
  float rs = rsqrtf(var + 1e-5f);
  float y0 = (x0 - mean) * rs * g[t] + bt[t];
  float y1 = (x1 - mean) * rs * g[t + 256] + bt[t + 256];
  if (pos) {
    int sp = row & (S_ - 1);
    y0 += pos[(size_t)sp * D_ + t];
    y1 += pos[(size_t)sp * D_ + t + 256];
  }
  hout[base + t] = f2bf(y0);
  hout[base + t + 256] = f2bf(y1);
}

// W[K][N] fp32 -> Wt[N][K] bf16, batched over layers via blockIdx.z
__global__ void wtrans_kernel(const float* __restrict__ W, ushort* __restrict__ Wt, int K, int N)
{
  __shared__ float tile[32][33];
  const float* Wl = W + (size_t)blockIdx.z * K * N;
  ushort* Wtl = Wt + (size_t)blockIdx.z * K * N;
  int n0 = blockIdx.x * 32, k0 = blockIdx.y * 32;
  int tx = threadIdx.x, ty = threadIdx.y;  // 32 x 8
#pragma unroll
  for (int r = 0; r < 4; ++r)
    tile[ty * 4 + r][tx] = Wl[(size_t)(k0 + ty * 4 + r) * N + n0 + tx];
  __syncthreads();
#pragma unroll
  for (int r = 0; r < 4; ++r)
    Wtl[(size_t)(n0 + ty * 4 + r) * K + k0 + tx] = f2bf(tile[tx][ty * 4 + r]);
}

__global__ void castx_kernel(const float* __restrict__ x, ushort* __restrict__ xb, int n)
{
  int i = blockIdx.x * blockDim.x + threadIdx.x;
  if (i < n) xb[i] = f2bf(x[i]);
}

__global__ __launch_bounds__(256)
void pool_partial_kernel(const ushort* __restrict__ h, float* __restrict__ pp)
{
  int b = blockIdx.x, ch = blockIdx.y;
  int t = threadIdx.x;
  float s0 = 0, s1 = 0;
  for (int r = 0; r < 128; ++r) {
    size_t base = ((size_t)b * S_ + ch * 128 + r) * D_;
    s0 += bf2f(h[base + t]);
    s1 += bf2f(h[base + t + 256]);
  }
  pp[(size_t)(b * 8 + ch) * D_ + t] = s0;
  pp[(size_t)(b * 8 + ch) * D_ + t + 256] = s1;
}

__global__ __launch_bounds__(256)
void head_kernel(const float* __restrict__ pp,
                 const float* __restrict__ w1, const float* __restrict__ b1,
                 const float* __restrict__ lg, const float* __restrict__ lb,
                 const float* __restrict__ w2, const float* __restrict__ b2,
                 float* __restrict__ out)
{
  __shared__ float pooled[D_];
  __shared__ float z[256];
  int b = blockIdx.x, t = threadIdx.x;
  for (int i = t; i < D_; i += 256) {
    float s = 0;
    for (int c = 0; c < 8; ++c) s += pp[(size_t)(b * 8 + c) * D_ + i];
    pooled[i] = s * (1.0f / S_);
  }
  __syncthreads();
  float acc = 0;
  for (int k = 0; k < D_; ++k) acc += pooled[k] * w1[(size_t)k * 256 + t];
  float zz = gelu_exact(acc + b1[t]);
  float s = zz, q = zz * zz;
#pragma unroll
  for (int m = 32; m > 0; m >>= 1) { s += __shfl_xor(s, m); q += __shfl_xor(q, m); }
  __shared__ float red[8];
  if ((t & 63) == 0) { red[(t >> 6) * 2] = s; red[(t >> 6) * 2 + 1] = q; }
  __syncthreads();
  s = red[0] + red[2] + red[4] + red[6];
  q = red[1] + red[3] + red[5] + red[7];
  float mean = s * (1.0f / 256), var = q * (1.0f / 256) - mean * mean;
  float rs = rsqrtf(var + 1e-5f);
  z[t] = (zz - mean) * rs * lg[t] + lb[t];
  __syncthreads();
  float o = 0;
  for (int k = 0; k < 256; ++k) o += z[k] * w2[(size_t)k * 256 + t];
  out[(size_t)b * 256 + t] = o + b2[t];
}

extern "C" void kernel_launch(void* const* d_in, const int* in_sizes, int n_in,
                              void* d_out, int out_size, void* d_ws, size_t ws_size,
                              hipStream_t stream)
{
  const float* x       = (const float*)d_in[0];
  const float* in_w    = (const float*)d_in[1];
  const float* in_b    = (const float*)d_in[2];
  const float* in_ln_g = (const float*)d_in[3];
  const float* in_ln_b = (const float*)d_in[4];
  const float* pos     = (const float*)d_in[5];
  const float* qkv_w   = (const float*)d_in[6];
  const float* qkv_b   = (const float*)d_in[7];
  const float* ao_w    = (const float*)d_in[8];
  const float* ao_b    = (const float*)d_in[9];
  const float* ff_w1   = (const float*)d_in[10];
  const float* ff_b1   = (const float*)d_in[11];
  const float* ff_w2   = (const float*)d_in[12];
  const float* ff_b2   = (const float*)d_in[13];
  const float* ln1_g   = (const float*)d_in[14];
  const float* ln1_b   = (const float*)d_in[15];
  const float* ln2_g   = (const float*)d_in[16];
  const float* ln2_b   = (const float*)d_in[17];
  const float* o_w1    = (const float*)d_in[18];
  const float* o_b1    = (const float*)d_in[19];
  const float* o_ln_g  = (const float*)d_in[20];
  const float* o_ln_b  = (const float*)d_in[21];
  const float* o_w2    = (const float*)d_in[22];
  const float* o_b2    = (const float*)d_in[23];

  char* wp = (char*)d_ws;
  auto alloc = [&](size_t bytes) {
    char* p = wp;
    wp += (bytes + 255) & ~(size_t)255;
    return p;
  };
  ushort* hb     = (ushort*)alloc((size_t)BS_ * D_ * 2);   // residual stream (bf16)
  ushort* tmpb   = (ushort*)alloc((size_t)BS_ * D_ * 2);   // bf16 GEMM outs
  ushort* big    = (ushort*)alloc((size_t)BS_ * FF_ * 2);  // qkv (Q,K) / ff1 bf16
  ushort* ctxb   = (ushort*)alloc((size_t)BS_ * D_ * 2);
  ushort* xb     = (ushort*)alloc((size_t)BS_ * IN_ * 2);
  ushort* vt     = (ushort*)alloc((size_t)B_ * H_ * HD_ * S_ * 2);
  float*  pp     = (float*) alloc((size_t)B_ * 8 * D_ * 4);
  ushort* in_wt  = (ushort*)alloc((size_t)D_ * IN_ * 2);
  ushort* qkv_wt = (ushort*)alloc((size_t)L_ * 3 * D_ * D_ * 2);
  ushort* ao_wt  = (ushort*)alloc((size_t)L_ * D_ * D_ * 2);
  ushort* ff1_wt = (ushort*)alloc((size_t)L_ * FF_ * D_ * 2);
  ushort* ff2_wt = (ushort*)alloc((size_t)L_ * D_ * FF_ * 2);
  (void)ws_size; (void)n_in; (void)in_sizes; (void)out_size;

  dim3 wb(32, 8);
  wtrans_kernel<<<dim3(D_ / 32, IN_ / 32, 1), wb, 0, stream>>>(in_w, in_wt, IN_, D_);
  wtrans_kernel<<<dim3(3 * D_ / 32, D_ / 32, L_), wb, 0, stream>>>(qkv_w, qkv_wt, D_, 3 * D_);
  wtrans_kernel<<<dim3(D_ / 32, D_ / 32, L_), wb, 0, stream>>>(ao_w, ao_wt, D_, D_);
  wtrans_kernel<<<dim3(FF_ / 32, D_ / 32, L_), wb, 0, stream>>>(ff_w1, ff1_wt, D_, FF_);
  wtrans_kernel<<<dim3(D_ / 32, FF_ / 32, L_), wb, 0, stream>>>(ff_w2, ff2_wt, FF_, D_);
  castx_kernel<<<BS_ * IN_ / 256, 256, 0, stream>>>(x, xb, BS_ * IN_);

  // input projection -> bf16 (K=64: nt=2)
  gemm_bt<128, 2, 2, 1><<<dim3(D_ / 128, BS_ / 128), 256, 0, stream>>>(
      xb, IN_, in_wt, IN_, in_b, tmpb, D_, IN_);
  ln512_kernel<<<BS_, 256, 0, stream>>>(tmpb, nullptr, in_ln_g, in_ln_b, pos, hb);

  for (int l = 0; l < L_; ++l) {
    const ushort* qwt = qkv_wt + (size_t)l * 3 * D_ * D_;
    const float*  qb  = qkv_b + (size_t)l * 3 * D_;
    // Q,K projection -> big cols [0,1024) (bf16)
    gemm_bt<128, 2, 2, 1><<<dim3(2 * D_ / 128, BS_ / 128), 256, 0, stream>>>(
        hb, D_, qwt, D_, qb, big, 3 * D_, D_);
    // V projection -> vt directly (transposed + pre-permuted)
    gemm_bt<128, 2, 2, 3><<<dim3(D_ / 128, BS_ / 128), 256, 0, stream>>>(
        hb, D_, qwt + (size_t)(2 * D_) * D_, D_, qb + 2 * D_, vt, S_, D_);
    // fused flash attention (QB=128, r15 config)
    flash_kernel<<<dim3(S_ / 128, B_ * H_), 512, 0, stream>>>(big, vt, ctxb);
    // attention output projection -> bf16
    gemm_bt<128, 2, 2, 1><<<dim3(D_ / 128, BS_ / 128), 256, 0, stream>>>(
        ctxb, D_, ao_wt + (size_t)l * D_ * D_, D_, ao_b + (size_t)l * D_,
        tmpb, D_, D_);
    ln512_kernel<<<BS_, 256, 0, stream>>>(tmpb, hb, ln1_g + (size_t)l * D_,
                                          ln1_b + (size_t)l * D_, nullptr, hb);
    // FF1 (gelu, bf16)
    gemm_bt<128, 2, 2, 2><<<dim3(FF_ / 128, BS_ / 128), 256, 0, stream>>>(
        hb, D_, ff1_wt + (size_t)l * FF_ * D_, D_, ff_b1 + (size_t)l * FF_,
        big, FF_, D_);
    // FF2 -> bf16
    gemm_bt<128, 2, 2, 1><<<dim3(D_ / 128, BS_ / 128), 256, 0, stream>>>(
        big, FF_, ff2_wt + (size_t)l * D_ * FF_, FF_, ff_b2 + (size_t)l * D_,
        tmpb, D_, FF_);
    ln512_kernel<<<BS_, 256, 0, stream>>>(tmpb, hb, ln2_g + (size_t)l * D_,
                                          ln2_b + (size_t)l * D_, nullptr, hb);
  }
  pool_partial_kernel<<<dim3(B_, 8), 256, 0, stream>>>(hb, pp);
  head_kernel<<<B_, 256, 0, stream>>>(pp, o_w1, o_b1, o_ln_g, o_ln_b, o_w2, o_b2,
                                      (float*)d_out);
}